// Round 1
// baseline (470.918 us; speedup 1.0000x reference)
//
#include <hip/hip_runtime.h>
#include <hip/hip_bf16.h>

#define NPTS 200000
#define INC  64
#define OUTC 128
#define KTAP 27
#define EPSV 1e-5f
#define BM   128

typedef __attribute__((ext_vector_type(8))) short bf16x8;
typedef __attribute__((ext_vector_type(4))) float f32x4;

__device__ __forceinline__ unsigned short f2bf(float f) {
  unsigned int u = __float_as_uint(f);
  return (unsigned short)((u + 0x7FFFu + ((u >> 16) & 1u)) >> 16);
}

// Build transposed + XOR-swizzled bf16 weight image in ws:
// image byte for (c, i): ((c*128 + 2*i) ^ ((c&7)<<4)), per-tap 16KB block.
__global__ void prep_weight(const float* __restrict__ w, unsigned char* __restrict__ img) {
  int kn = blockIdx.x;
  const float* wk = w + kn * (INC * OUTC);
  unsigned char* dst = img + kn * (INC * OUTC * 2);
  for (int e = threadIdx.x; e < INC * OUTC; e += blockDim.x) {
    int c = e >> 6;   // 0..127
    int i = e & 63;   // 0..63
    unsigned short h = f2bf(wk[i * OUTC + c]);
    unsigned int byte = (unsigned)(c * (INC * 2) + i * 2);
    byte ^= ((unsigned)(c & 7)) << 4;
    *(unsigned short*)(dst + byte) = h;
  }
}

__global__ __launch_bounds__(256) void conv_main(
    const float* __restrict__ feats,
    const int*   __restrict__ nmap,
    const unsigned char* __restrict__ wimg,
    float* __restrict__ out,
    float* __restrict__ gsum,
    float* __restrict__ gsumsq)
{
  __shared__ __align__(16) unsigned char ldsA[BM * INC * 2];    // 16KB
  __shared__ __align__(16) unsigned char ldsB[OUTC * INC * 2];  // 16KB
  __shared__ float lsum[OUTC];
  __shared__ float lsumsq[OUTC];

  const int t    = threadIdx.x;
  const int lane = t & 63;
  const int w    = t >> 6;        // wave 0..3
  const int wm   = w >> 1;        // 0..1  (m half)
  const int wn   = w & 1;         // 0..1  (n half)
  const int n0   = blockIdx.x * BM;
  const int lr   = lane & 15;     // 16-dim index within fragment
  const int lg   = lane >> 4;     // k-group / row-group

  if (t < OUTC) { lsum[t] = 0.f; lsumsq[t] = 0.f; }

  f32x4 zv = {0.f, 0.f, 0.f, 0.f};
  f32x4 acc[4][4];
  #pragma unroll
  for (int i = 0; i < 4; ++i)
    #pragma unroll
    for (int j = 0; j < 4; ++j) acc[i][j] = zv;

  for (int kn = 0; kn < KTAP; ++kn) {
    __syncthreads();
    // ---- stage B: linear 16KB copy of pre-swizzled weight image ----
    {
      const float4* src = (const float4*)(wimg + kn * 16384);
      float4* dstv = (float4*)ldsB;
      #pragma unroll
      for (int j = 0; j < 4; ++j) dstv[j * 256 + t] = src[j * 256 + t];
    }
    // ---- stage A: gather fp32 rows, cvt to bf16, swizzled LDS write ----
    {
      const int base = kn * NPTS;
      #pragma unroll
      for (int j = 0; j < 8; ++j) {
        int fidx = j * 256 + t;        // 0..2047
        int row  = fidx >> 4;          // 0..127
        int c4   = fidx & 15;          // float4 index within row
        int n    = n0 + row;
        int g    = (n < NPTS) ? nmap[base + n] : -1;
        float4 v = make_float4(0.f, 0.f, 0.f, 0.f);
        if (g >= 0) v = ((const float4*)feats)[g * 16 + c4];
        ushort4 h;
        h.x = f2bf(v.x); h.y = f2bf(v.y); h.z = f2bf(v.z); h.w = f2bf(v.w);
        unsigned int byte = (unsigned)(row * 128 + c4 * 8);
        byte ^= ((unsigned)(row & 7)) << 4;
        *(ushort4*)(ldsA + byte) = h;
      }
    }
    __syncthreads();
    // ---- compute: 2 k-slices of 32, 4x4 fragments of 16x16 ----
    #pragma unroll
    for (int kk = 0; kk < 2; ++kk) {
      bf16x8 av[4], bv[4];
      const int kb = kk * 64 + lg * 16;   // byte offset of 8 bf16 k-elems
      #pragma unroll
      for (int mf = 0; mf < 4; ++mf) {
        int row = wm * 64 + mf * 16 + lr;
        unsigned int byte = ((unsigned)(row * 128 + kb)) ^ (((unsigned)(row & 7)) << 4);
        av[mf] = *(const bf16x8*)(ldsA + byte);
      }
      #pragma unroll
      for (int nf = 0; nf < 4; ++nf) {
        int c = wn * 64 + nf * 16 + lr;
        unsigned int byte = ((unsigned)(c * 128 + kb)) ^ (((unsigned)(c & 7)) << 4);
        bv[nf] = *(const bf16x8*)(ldsB + byte);
      }
      #pragma unroll
      for (int mf = 0; mf < 4; ++mf)
        #pragma unroll
        for (int nf = 0; nf < 4; ++nf)
          acc[mf][nf] = __builtin_amdgcn_mfma_f32_16x16x32_bf16(av[mf], bv[nf], acc[mf][nf], 0, 0, 0);
    }
  }

  // ---- epilogue: raw out + per-channel partial sums ----
  #pragma unroll
  for (int nf = 0; nf < 4; ++nf) {
    int c = wn * 64 + nf * 16 + lr;
    float s = 0.f, s2 = 0.f;
    #pragma unroll
    for (int mf = 0; mf < 4; ++mf) {
      #pragma unroll
      for (int r = 0; r < 4; ++r) {
        float v = acc[mf][nf][r];
        s += v; s2 += v * v;
        int row = wm * 64 + mf * 16 + lg * 4 + r;
        int n = n0 + row;
        if (n < NPTS) out[(long)n * OUTC + c] = v;
      }
    }
    atomicAdd(&lsum[c], s);
    atomicAdd(&lsumsq[c], s2);
  }
  __syncthreads();
  if (t < OUTC) {
    atomicAdd(&gsum[t],   lsum[t]);
    atomicAdd(&gsumsq[t], lsumsq[t]);
  }
}

__global__ void finalize_stats(const float* __restrict__ gsum,
                               const float* __restrict__ gsumsq,
                               const float* __restrict__ gamma,
                               const float* __restrict__ beta,
                               float* __restrict__ scale,
                               float* __restrict__ shift) {
  int c = threadIdx.x;
  if (c < OUTC) {
    float mean = gsum[c] * (1.0f / (float)NPTS);
    float var  = gsumsq[c] * (1.0f / (float)NPTS) - mean * mean;
    var = fmaxf(var, 0.f);
    float sc = gamma[c] * rsqrtf(var + EPSV);
    scale[c] = sc;
    shift[c] = beta[c] - mean * sc;
  }
}

__global__ __launch_bounds__(256) void norm_relu(float* __restrict__ out,
                                                 const float* __restrict__ scale,
                                                 const float* __restrict__ shift) {
  __shared__ float s_sc[OUTC], s_sh[OUTC];
  if (threadIdx.x < OUTC) {
    s_sc[threadIdx.x] = scale[threadIdx.x];
    s_sh[threadIdx.x] = shift[threadIdx.x];
  }
  __syncthreads();
  const long total = (long)NPTS * OUTC / 4;   // 6.4M float4
  for (long i = (long)blockIdx.x * blockDim.x + threadIdx.x; i < total;
       i += (long)gridDim.x * blockDim.x) {
    float4 v = ((float4*)out)[i];
    int cb = (int)(i & 31) * 4;   // row length 128 = 32 float4
    v.x = fmaxf(v.x * s_sc[cb + 0] + s_sh[cb + 0], 0.f);
    v.y = fmaxf(v.y * s_sc[cb + 1] + s_sh[cb + 1], 0.f);
    v.z = fmaxf(v.z * s_sc[cb + 2] + s_sh[cb + 2], 0.f);
    v.w = fmaxf(v.w * s_sc[cb + 3] + s_sh[cb + 3], 0.f);
    ((float4*)out)[i] = v;
  }
}

extern "C" void kernel_launch(void* const* d_in, const int* in_sizes, int n_in,
                              void* d_out, int out_size, void* d_ws, size_t ws_size,
                              hipStream_t stream) {
  (void)in_sizes; (void)n_in; (void)out_size; (void)ws_size;
  const float* feats  = (const float*)d_in[0];
  const float* weight = (const float*)d_in[1];
  const float* gamma  = (const float*)d_in[2];
  const float* beta   = (const float*)d_in[3];
  const int*   nmap   = (const int*)d_in[4];
  float* out = (float*)d_out;

  unsigned char* ws = (unsigned char*)d_ws;
  unsigned char* wimg = ws;                       // 27 * 16384 = 442368 B
  float* gsum   = (float*)(ws + 442368);          // 128
  float* gsumsq = gsum + 128;                     // 128
  float* scale  = gsumsq + 128;                   // 128
  float* shift  = scale + 128;                    // 128

  hipMemsetAsync(gsum, 0, 256 * sizeof(float), stream);
  prep_weight<<<KTAP, 256, 0, stream>>>(weight, wimg);
  int grid = (NPTS + BM - 1) / BM;  // 1563
  conv_main<<<grid, 256, 0, stream>>>(feats, nmap, wimg, out, gsum, gsumsq);
  finalize_stats<<<1, 128, 0, stream>>>(gsum, gsumsq, gamma, beta, scale, shift);
  norm_relu<<<4096, 256, 0, stream>>>(out, scale, shift);
}

// Round 3
// 291.018 us; speedup vs baseline: 1.6182x; 1.6182x over previous
//
#include <hip/hip_runtime.h>
#include <hip/hip_bf16.h>

#define NPTS 200000
#define INC  64
#define OUTC 128
#define KTAP 27
#define EPSV 1e-5f
#define BM   128

typedef __attribute__((ext_vector_type(8))) short bf16x8;
typedef __attribute__((ext_vector_type(4))) float f32x4;

__device__ __forceinline__ unsigned short f2bf(float f) {
  unsigned int u = __float_as_uint(f);
  return (unsigned short)((u + 0x7FFFu + ((u >> 16) & 1u)) >> 16);
}

// Transposed + XOR-swizzled bf16 weight image: per-tap 16KB block,
// byte for (c,i) = (c*128 + 2*i) ^ ((c&7)<<4).
__global__ void prep_weight(const float* __restrict__ w, unsigned char* __restrict__ img) {
  int kn = blockIdx.x;
  const float* wk = w + kn * (INC * OUTC);
  unsigned char* dst = img + kn * (INC * OUTC * 2);
  for (int e = threadIdx.x; e < INC * OUTC; e += blockDim.x) {
    int c = e >> 6;
    int i = e & 63;
    unsigned short h = f2bf(wk[i * OUTC + c]);
    unsigned int byte = (unsigned)(c * (INC * 2) + i * 2);
    byte ^= ((unsigned)(c & 7)) << 4;
    *(unsigned short*)(dst + byte) = h;
  }
}

// feats fp32 (N x 64) -> bf16 rows of 128B. 8 elems/thread, 6250 blocks x 256.
__global__ __launch_bounds__(256) void prep_feats(const float* __restrict__ f,
                                                  unsigned short* __restrict__ o) {
  size_t i = (size_t)blockIdx.x * 256 + threadIdx.x;   // 1.6M threads exactly
  float4 a = ((const float4*)f)[i * 2];
  float4 b = ((const float4*)f)[i * 2 + 1];
  ushort4 ha = make_ushort4(f2bf(a.x), f2bf(a.y), f2bf(a.z), f2bf(a.w));
  ushort4 hb = make_ushort4(f2bf(b.x), f2bf(b.y), f2bf(b.z), f2bf(b.w));
  ((ushort4*)o)[i * 2]     = ha;
  ((ushort4*)o)[i * 2 + 1] = hb;
}

template<int FB>
__global__ __launch_bounds__(256) void conv_main(
    const float* __restrict__ feats,
    const unsigned short* __restrict__ fbf,
    const int*   __restrict__ nmap,
    const unsigned char* __restrict__ wimg,
    float* __restrict__ out,
    float* __restrict__ gsum,
    float* __restrict__ gsumsq)
{
  __shared__ __align__(16) unsigned char ldsA[BM * 128];    // 16KB bf16 A tile
  __shared__ __align__(16) unsigned char ldsB[OUTC * 128];  // 16KB bf16 B tile
  __shared__ float lsum[OUTC];
  __shared__ float lsumsq[OUTC];

  const int t    = threadIdx.x;
  const int lane = t & 63;
  const int w    = t >> 6;
  const int wm   = w >> 1;
  const int wn   = w & 1;
  const int n0   = blockIdx.x * BM;
  const int lr   = lane & 15;
  const int lg   = lane >> 4;
  const int row_ = t >> 3;      // staging row within 32-row group
  const int c8_  = t & 7;       // 16B chunk within 128B row

  if (t < OUTC) { lsum[t] = 0.f; lsumsq[t] = 0.f; }

  f32x4 zv = {0.f, 0.f, 0.f, 0.f};
  f32x4 acc[4][4];
  #pragma unroll
  for (int i = 0; i < 4; ++i)
    #pragma unroll
    for (int j = 0; j < 4; ++j) acc[i][j] = zv;

  int nrow[4];
  #pragma unroll
  for (int j = 0; j < 4; ++j) nrow[j] = n0 + j * 32 + row_;

  // ---- prologue: gather tap 0, prefetch nmap for taps 1 and 2 ----
  int idxA[4], idxB[4];
  bf16x8 vA[4];
  {
    int g0[4];
    #pragma unroll
    for (int j = 0; j < 4; ++j)
      g0[j] = (nrow[j] < NPTS) ? nmap[nrow[j]] : -1;
    #pragma unroll
    for (int j = 0; j < 4; ++j) {
      int g = g0[j];
      if (FB) {
        vA[j] = (g >= 0) ? *(const bf16x8*)(fbf + (size_t)g * 64 + c8_ * 8)
                         : (bf16x8)(short)0;
      } else {
        f32x4 a = zv, b = zv;
        if (g >= 0) {
          const f32x4* p = (const f32x4*)(feats + (size_t)g * 64 + c8_ * 8);
          a = p[0]; b = p[1];
        }
        bf16x8 r;
        r[0]=(short)f2bf(a[0]); r[1]=(short)f2bf(a[1]); r[2]=(short)f2bf(a[2]); r[3]=(short)f2bf(a[3]);
        r[4]=(short)f2bf(b[0]); r[5]=(short)f2bf(b[1]); r[6]=(short)f2bf(b[2]); r[7]=(short)f2bf(b[3]);
        vA[j] = r;
      }
    }
    #pragma unroll
    for (int j = 0; j < 4; ++j)
      idxA[j] = (nrow[j] < NPTS) ? nmap[1 * NPTS + nrow[j]] : -1;
    #pragma unroll
    for (int j = 0; j < 4; ++j)
      idxB[j] = (nrow[j] < NPTS) ? nmap[2 * NPTS + nrow[j]] : -1;
  }

  for (int kn = 0; kn < KTAP; ++kn) {
    // ---- P1: B tile via global_load_lds (pre-swizzled linear image) ----
    {
      const unsigned char* src = wimg + kn * 16384 + (size_t)t * 16;
      unsigned char* dst = ldsB + t * 16;
      #pragma unroll
      for (int j = 0; j < 4; ++j)
        __builtin_amdgcn_global_load_lds(
            (const __attribute__((address_space(1))) void*)(src + j * 4096),
            (__attribute__((address_space(3))) void*)(dst + j * 4096),
            16, 0, 0);
    }
    // ---- P1b: write tap-kn A data (gathered last iter) to LDS, swizzled ----
    #pragma unroll
    for (int j = 0; j < 4; ++j) {
      int row = j * 32 + row_;
      unsigned int byte = ((unsigned)(row * 128 + c8_ * 16)) ^ (((unsigned)(row & 7)) << 4);
      *(bf16x8*)(ldsA + byte) = vA[j];
    }
    __syncthreads();

    // ---- P3: issue gathers for tap kn+1 (latency hides under P4) ----
    if (kn + 1 < KTAP) {
      #pragma unroll
      for (int j = 0; j < 4; ++j) {
        int g = idxA[j];
        if (FB) {
          vA[j] = (g >= 0) ? *(const bf16x8*)(fbf + (size_t)g * 64 + c8_ * 8)
                           : (bf16x8)(short)0;
        } else {
          f32x4 a = zv, b = zv;
          if (g >= 0) {
            const f32x4* p = (const f32x4*)(feats + (size_t)g * 64 + c8_ * 8);
            a = p[0]; b = p[1];
          }
          bf16x8 r;
          r[0]=(short)f2bf(a[0]); r[1]=(short)f2bf(a[1]); r[2]=(short)f2bf(a[2]); r[3]=(short)f2bf(a[3]);
          r[4]=(short)f2bf(b[0]); r[5]=(short)f2bf(b[1]); r[6]=(short)f2bf(b[2]); r[7]=(short)f2bf(b[3]);
          vA[j] = r;
        }
      }
    }
    // ---- P3b: prefetch nmap for tap kn+3 ----
    int idxT[4];
    if (kn + 3 < KTAP) {
      #pragma unroll
      for (int j = 0; j < 4; ++j)
        idxT[j] = (nrow[j] < NPTS) ? nmap[(kn + 3) * NPTS + nrow[j]] : -1;
    } else {
      #pragma unroll
      for (int j = 0; j < 4; ++j) idxT[j] = -1;
    }

    // ---- P4: compute tap kn ----
    #pragma unroll
    for (int kk = 0; kk < 2; ++kk) {
      bf16x8 av[4], bv[4];
      const int kb = kk * 64 + lg * 16;
      #pragma unroll
      for (int mf = 0; mf < 4; ++mf) {
        int row = wm * 64 + mf * 16 + lr;
        unsigned int byte = ((unsigned)(row * 128 + kb)) ^ (((unsigned)(row & 7)) << 4);
        av[mf] = *(const bf16x8*)(ldsA + byte);
      }
      #pragma unroll
      for (int nf = 0; nf < 4; ++nf) {
        int c = wn * 64 + nf * 16 + lr;
        unsigned int byte = ((unsigned)(c * 128 + kb)) ^ (((unsigned)(c & 7)) << 4);
        bv[nf] = *(const bf16x8*)(ldsB + byte);
      }
      #pragma unroll
      for (int mf = 0; mf < 4; ++mf)
        #pragma unroll
        for (int nf = 0; nf < 4; ++nf)
          acc[mf][nf] = __builtin_amdgcn_mfma_f32_16x16x32_bf16(av[mf], bv[nf], acc[mf][nf], 0, 0, 0);
    }
    #pragma unroll
    for (int j = 0; j < 4; ++j) { idxA[j] = idxB[j]; idxB[j] = idxT[j]; }
    __syncthreads();
  }

  // ---- epilogue: raw out + per-channel partial sums ----
  #pragma unroll
  for (int nf = 0; nf < 4; ++nf) {
    int c = wn * 64 + nf * 16 + lr;
    float s = 0.f, s2 = 0.f;
    #pragma unroll
    for (int mf = 0; mf < 4; ++mf) {
      #pragma unroll
      for (int r = 0; r < 4; ++r) {
        float v = acc[mf][nf][r];
        s += v; s2 += v * v;
        int row = wm * 64 + mf * 16 + lg * 4 + r;
        int n = n0 + row;
        if (n < NPTS) out[(size_t)n * OUTC + c] = v;
      }
    }
    atomicAdd(&lsum[c], s);
    atomicAdd(&lsumsq[c], s2);
  }
  __syncthreads();
  if (t < OUTC) {
    atomicAdd(&gsum[t],   lsum[t]);
    atomicAdd(&gsumsq[t], lsumsq[t]);
  }
}

__global__ void finalize_stats(const float* __restrict__ gsum,
                               const float* __restrict__ gsumsq,
                               const float* __restrict__ gamma,
                               const float* __restrict__ beta,
                               float* __restrict__ scale,
                               float* __restrict__ shift) {
  int c = threadIdx.x;
  if (c < OUTC) {
    float mean = gsum[c] * (1.0f / (float)NPTS);
    float var  = gsumsq[c] * (1.0f / (float)NPTS) - mean * mean;
    var = fmaxf(var, 0.f);
    float sc = gamma[c] * rsqrtf(var + EPSV);
    scale[c] = sc;
    shift[c] = beta[c] - mean * sc;
  }
}

__global__ __launch_bounds__(256) void norm_relu(float* __restrict__ out,
                                                 const float* __restrict__ scale,
                                                 const float* __restrict__ shift) {
  __shared__ float s_sc[OUTC], s_sh[OUTC];
  if (threadIdx.x < OUTC) {
    s_sc[threadIdx.x] = scale[threadIdx.x];
    s_sh[threadIdx.x] = shift[threadIdx.x];
  }
  __syncthreads();
  const long total = (long)NPTS * OUTC / 4;
  for (long i = (long)blockIdx.x * blockDim.x + threadIdx.x; i < total;
       i += (long)gridDim.x * blockDim.x) {
    float4 v = ((float4*)out)[i];
    int cb = (int)(i & 31) * 4;
    v.x = fmaxf(v.x * s_sc[cb + 0] + s_sh[cb + 0], 0.f);
    v.y = fmaxf(v.y * s_sc[cb + 1] + s_sh[cb + 1], 0.f);
    v.z = fmaxf(v.z * s_sc[cb + 2] + s_sh[cb + 2], 0.f);
    v.w = fmaxf(v.w * s_sc[cb + 3] + s_sh[cb + 3], 0.f);
    ((float4*)out)[i] = v;
  }
}

extern "C" void kernel_launch(void* const* d_in, const int* in_sizes, int n_in,
                              void* d_out, int out_size, void* d_ws, size_t ws_size,
                              hipStream_t stream) {
  (void)in_sizes; (void)n_in; (void)out_size;
  const float* feats  = (const float*)d_in[0];
  const float* weight = (const float*)d_in[1];
  const float* gamma  = (const float*)d_in[2];
  const float* beta   = (const float*)d_in[3];
  const int*   nmap   = (const int*)d_in[4];
  float* out = (float*)d_out;

  unsigned char* ws = (unsigned char*)d_ws;
  const size_t FBF_BYTES  = (size_t)NPTS * 64 * 2;     // 25,600,000
  const size_t WIMG_BYTES = (size_t)KTAP * 16384;      // 442,368
  bool use_bf = ws_size >= FBF_BYTES + WIMG_BYTES + 2048;

  unsigned short* fbf;
  unsigned char* wimg;
  float* gsum;
  if (use_bf) {
    fbf  = (unsigned short*)ws;
    wimg = ws + FBF_BYTES;
    gsum = (float*)(ws + FBF_BYTES + WIMG_BYTES);
  } else {
    fbf  = nullptr;
    wimg = ws;
    gsum = (float*)(ws + WIMG_BYTES);
  }
  float* gsumsq = gsum + 128;
  float* scale  = gsumsq + 128;
  float* shift  = scale + 128;

  hipMemsetAsync(gsum, 0, 256 * sizeof(float), stream);
  prep_weight<<<KTAP, 256, 0, stream>>>(weight, wimg);
  int grid = (NPTS + BM - 1) / BM;  // 1563
  if (use_bf) {
    prep_feats<<<6250, 256, 0, stream>>>(feats, fbf);
    conv_main<1><<<grid, 256, 0, stream>>>(feats, fbf, nmap, wimg, out, gsum, gsumsq);
  } else {
    conv_main<0><<<grid, 256, 0, stream>>>(feats, fbf, nmap, wimg, out, gsum, gsumsq);
  }
  finalize_stats<<<1, 128, 0, stream>>>(gsum, gsumsq, gamma, beta, scale, shift);
  norm_relu<<<4096, 256, 0, stream>>>(out, scale, shift);
}

// Round 4
// 288.993 us; speedup vs baseline: 1.6295x; 1.0070x over previous
//
#include <hip/hip_runtime.h>
#include <hip/hip_bf16.h>

#define NPTS 200000
#define INC  64
#define OUTC 128
#define KTAP 27
#define EPSV 1e-5f
#define BM   64

typedef __attribute__((ext_vector_type(8))) short bf16x8;
typedef __attribute__((ext_vector_type(4))) float f32x4;

__device__ __forceinline__ unsigned short f2bf(float f) {
  unsigned int u = __float_as_uint(f);
  return (unsigned short)((u + 0x7FFFu + ((u >> 16) & 1u)) >> 16);
}

// Transposed (unswizzled) bf16 weight image: per-tap 16KB block,
// byte for (c,i) = c*128 + 2*i.  Read directly into registers (L2-hot).
__global__ void prep_weight(const float* __restrict__ w, unsigned char* __restrict__ img) {
  int kn = blockIdx.x;
  const float* wk = w + kn * (INC * OUTC);
  unsigned char* dst = img + kn * (INC * OUTC * 2);
  for (int e = threadIdx.x; e < INC * OUTC; e += blockDim.x) {
    int c = e >> 6;
    int i = e & 63;
    unsigned short h = f2bf(wk[i * OUTC + c]);
    *(unsigned short*)(dst + c * 128 + i * 2) = h;
  }
}

// feats fp32 (N x 64) -> bf16 rows of 128B.
__global__ __launch_bounds__(256) void prep_feats(const float* __restrict__ f,
                                                  unsigned short* __restrict__ o) {
  size_t i = (size_t)blockIdx.x * 256 + threadIdx.x;   // 1.6M threads exactly
  float4 a = ((const float4*)f)[i * 2];
  float4 b = ((const float4*)f)[i * 2 + 1];
  ushort4 ha = make_ushort4(f2bf(a.x), f2bf(a.y), f2bf(a.z), f2bf(a.w));
  ushort4 hb = make_ushort4(f2bf(b.x), f2bf(b.y), f2bf(b.z), f2bf(b.w));
  ((ushort4*)o)[i * 2]     = ha;
  ((ushort4*)o)[i * 2 + 1] = hb;
}

__global__ __launch_bounds__(256, 5) void conv_main(
    const unsigned short* __restrict__ fbf,
    const int*   __restrict__ nmap,
    const unsigned char* __restrict__ wimg,
    float* __restrict__ out,
    float* __restrict__ gsum,
    float* __restrict__ gsumsq)
{
  // double-buffered A tile: 2 x (64 rows x 128B), XOR-swizzled rows
  __shared__ __align__(16) unsigned char ldsA[2][BM * 128];   // 16KB
  __shared__ float lsum[OUTC];
  __shared__ float lsumsq[OUTC];

  const int t    = threadIdx.x;
  const int lane = t & 63;
  const int w    = t >> 6;        // wave 0..3 -> col quarter w*32
  const int n0   = blockIdx.x * BM;
  const int lr   = lane & 15;
  const int lg   = lane >> 4;
  const int row_ = t >> 3;        // 0..31 (staging row in lower half)
  const int c8_  = t & 7;         // 16B chunk within 128B row

  if (t < OUTC) { lsum[t] = 0.f; lsumsq[t] = 0.f; }

  f32x4 zv = {0.f, 0.f, 0.f, 0.f};
  f32x4 acc[4][2];
  #pragma unroll
  for (int i = 0; i < 4; ++i) { acc[i][0] = zv; acc[i][1] = zv; }

  const int na = n0 + row_;        // my row (lower 32)
  const int nb = na + 32;          // my row (upper 32)

  // ---- prologue: gather tap 0; idx for taps 1,2 in regs ----
  bf16x8 vA0, vA1;
  int i1a, i1b, i2a, i2b;
  {
    int g0a = nmap[na], g0b = nmap[nb];
    vA0 = (g0a >= 0) ? *(const bf16x8*)(fbf + g0a * 64 + c8_ * 8) : (bf16x8)(short)0;
    vA1 = (g0b >= 0) ? *(const bf16x8*)(fbf + g0b * 64 + c8_ * 8) : (bf16x8)(short)0;
    i1a = nmap[1 * NPTS + na]; i1b = nmap[1 * NPTS + nb];
    i2a = nmap[2 * NPTS + na]; i2b = nmap[2 * NPTS + nb];
  }

  const unsigned wsw = ((unsigned)(row_ & 7)) << 4;   // same for row_ and row_+32

  for (int kn = 0; kn < KTAP; ++kn) {
    unsigned char* bufA = ldsA[kn & 1];
    // ---- write A(kn) to this tap's buffer (swizzled) ----
    {
      unsigned int b0 = ((unsigned)(row_ * 128 + c8_ * 16)) ^ wsw;
      unsigned int b1 = ((unsigned)((row_ + 32) * 128 + c8_ * 16)) ^ wsw;
      *(bf16x8*)(bufA + b0) = vA0;
      *(bf16x8*)(bufA + b1) = vA1;
    }
    // raw barrier: own LDS writes drained, but in-flight global loads SURVIVE
    asm volatile("s_waitcnt lgkmcnt(0)" ::: "memory");
    __builtin_amdgcn_s_barrier();

    // ---- issue gathers for tap kn+1 (budget: full compute phase + barrier) ----
    if (kn + 1 < KTAP) {
      vA0 = (i1a >= 0) ? *(const bf16x8*)(fbf + i1a * 64 + c8_ * 8) : (bf16x8)(short)0;
      vA1 = (i1b >= 0) ? *(const bf16x8*)(fbf + i1b * 64 + c8_ * 8) : (bf16x8)(short)0;
    }
    i1a = i2a; i1b = i2b;
    if (kn + 3 < KTAP) {
      i2a = nmap[(kn + 3) * NPTS + na];
      i2b = nmap[(kn + 3) * NPTS + nb];
    }

    // ---- compute tap kn: A from LDS, B from L2-resident image ----
    const unsigned char* wb = wimg + kn * 16384;
    #pragma unroll
    for (int kk = 0; kk < 2; ++kk) {
      const int kb = kk * 64 + lg * 16;
      bf16x8 av[4], bv[2];
      #pragma unroll
      for (int mf = 0; mf < 4; ++mf) {
        int row = mf * 16 + lr;
        unsigned int byte = ((unsigned)(row * 128 + kb)) ^ (((unsigned)(row & 7)) << 4);
        av[mf] = *(const bf16x8*)(bufA + byte);
      }
      #pragma unroll
      for (int nf = 0; nf < 2; ++nf) {
        int c = w * 32 + nf * 16 + lr;
        bv[nf] = *(const bf16x8*)(wb + c * 128 + kb);
      }
      #pragma unroll
      for (int mf = 0; mf < 4; ++mf)
        #pragma unroll
        for (int nf = 0; nf < 2; ++nf)
          acc[mf][nf] = __builtin_amdgcn_mfma_f32_16x16x32_bf16(av[mf], bv[nf], acc[mf][nf], 0, 0, 0);
    }
    // no second barrier: next tap writes the OTHER buffer (one-barrier dbuf)
  }

  // ---- epilogue: raw out + per-channel partial sums ----
  #pragma unroll
  for (int nf = 0; nf < 2; ++nf) {
    int c = w * 32 + nf * 16 + lr;
    float s = 0.f, s2 = 0.f;
    #pragma unroll
    for (int mf = 0; mf < 4; ++mf) {
      #pragma unroll
      for (int r = 0; r < 4; ++r) {
        float v = acc[mf][nf][r];
        s += v; s2 += v * v;
        int n = n0 + mf * 16 + lg * 4 + r;   // grid is exact: n < NPTS always
        out[(size_t)n * OUTC + c] = v;
      }
    }
    atomicAdd(&lsum[c], s);
    atomicAdd(&lsumsq[c], s2);
  }
  __syncthreads();
  if (t < OUTC) {
    atomicAdd(&gsum[t],   lsum[t]);
    atomicAdd(&gsumsq[t], lsumsq[t]);
  }
}

__global__ void finalize_stats(const float* __restrict__ gsum,
                               const float* __restrict__ gsumsq,
                               const float* __restrict__ gamma,
                               const float* __restrict__ beta,
                               float* __restrict__ scale,
                               float* __restrict__ shift) {
  int c = threadIdx.x;
  if (c < OUTC) {
    float mean = gsum[c] * (1.0f / (float)NPTS);
    float var  = gsumsq[c] * (1.0f / (float)NPTS) - mean * mean;
    var = fmaxf(var, 0.f);
    float sc = gamma[c] * rsqrtf(var + EPSV);
    scale[c] = sc;
    shift[c] = beta[c] - mean * sc;
  }
}

__global__ __launch_bounds__(256) void norm_relu(float* __restrict__ out,
                                                 const float* __restrict__ scale,
                                                 const float* __restrict__ shift) {
  __shared__ float s_sc[OUTC], s_sh[OUTC];
  if (threadIdx.x < OUTC) {
    s_sc[threadIdx.x] = scale[threadIdx.x];
    s_sh[threadIdx.x] = shift[threadIdx.x];
  }
  __syncthreads();
  const long total = (long)NPTS * OUTC / 4;
  for (long i = (long)blockIdx.x * blockDim.x + threadIdx.x; i < total;
       i += (long)gridDim.x * blockDim.x) {
    float4 v = ((float4*)out)[i];
    int cb = (int)(i & 31) * 4;
    v.x = fmaxf(v.x * s_sc[cb + 0] + s_sh[cb + 0], 0.f);
    v.y = fmaxf(v.y * s_sc[cb + 1] + s_sh[cb + 1], 0.f);
    v.z = fmaxf(v.z * s_sc[cb + 2] + s_sh[cb + 2], 0.f);
    v.w = fmaxf(v.w * s_sc[cb + 3] + s_sh[cb + 3], 0.f);
    ((float4*)out)[i] = v;
  }
}

extern "C" void kernel_launch(void* const* d_in, const int* in_sizes, int n_in,
                              void* d_out, int out_size, void* d_ws, size_t ws_size,
                              hipStream_t stream) {
  (void)in_sizes; (void)n_in; (void)out_size; (void)ws_size;
  const float* feats  = (const float*)d_in[0];
  const float* weight = (const float*)d_in[1];
  const float* gamma  = (const float*)d_in[2];
  const float* beta   = (const float*)d_in[3];
  const int*   nmap   = (const int*)d_in[4];
  float* out = (float*)d_out;

  unsigned char* ws = (unsigned char*)d_ws;
  const size_t FBF_BYTES  = (size_t)NPTS * 64 * 2;     // 25,600,000
  const size_t WIMG_BYTES = (size_t)KTAP * 16384;      // 442,368
  unsigned short* fbf = (unsigned short*)ws;
  unsigned char* wimg = ws + FBF_BYTES;
  float* gsum   = (float*)(ws + FBF_BYTES + WIMG_BYTES);
  float* gsumsq = gsum + 128;
  float* scale  = gsumsq + 128;
  float* shift  = scale + 128;

  hipMemsetAsync(gsum, 0, 256 * sizeof(float), stream);
  prep_weight<<<KTAP, 256, 0, stream>>>(weight, wimg);
  prep_feats<<<6250, 256, 0, stream>>>(feats, fbf);
  int grid = NPTS / BM;  // 3125 exactly
  conv_main<<<grid, 256, 0, stream>>>(fbf, nmap, wimg, out, gsum, gsumsq);
  finalize_stats<<<1, 128, 0, stream>>>(gsum, gsumsq, gamma, beta, scale, shift);
  norm_relu<<<4096, 256, 0, stream>>>(out, scale, shift);
}